// Round 7
// baseline (81.583 us; speedup 1.0000x reference)
//
#include <hip/hip_runtime.h>

#define NB 128
#define NL 2048
#define NH 256
#define NSEG 32
#define SEGLEN (NL / NSEG)   // 64
#define RCHUNK 16            // timesteps per reduce-chunk in pass3
#define NCHK (SEGLEN / RCHUNK) // 4
#define PBPITCH 9            // uints per channel row in pbuf (2-way banks = free)
#define CHUNK 32             // fallback kernel chunking
#define NCHUNK (NL / CHUNK)
#define WORDS (CHUNK * 3)

typedef float f32x2 __attribute__((ext_vector_type(2)));
typedef __fp16 f16x2 __attribute__((ext_vector_type(2)));

__device__ __forceinline__ float fexp2(float v) { return __builtin_amdgcn_exp2f(v); }
__device__ __forceinline__ float frcp(float v)  { return __builtin_amdgcn_rcpf(v); }

__device__ __forceinline__ f32x2 pkfma(f32x2 a, f32x2 b, f32x2 c) {
#if __has_builtin(__builtin_elementwise_fma)
    return __builtin_elementwise_fma(a, b, c);   // -> v_pk_fma_f32
#else
    f32x2 r; r.x = fmaf(a.x, b.x, c.x); r.y = fmaf(a.y, b.y, c.y); return r;
#endif
}
__device__ __forceinline__ f32x2 splat2(float v) { f32x2 r; r.x = v; r.y = v; return r; }

union U32H2 { unsigned int u; f16x2 h; };

// ---------------------------------------------------------------------------
// Fold K=3 projection through Wz/Wh, pre-scaled by exp2 constants.
// 16 blocks x 256 threads: jj = tid&15 -> channel, hs = tid>>4 -> h-slice.
// ---------------------------------------------------------------------------
__global__ __launch_bounds__(256) void fold_kernel(
        const float* __restrict__ Wp, const float* __restrict__ bp,
        const float* __restrict__ Wz, const float* __restrict__ bz,
        const float* __restrict__ Wh, const float* __restrict__ bh,
        float* __restrict__ wsW) {
    const int tid = threadIdx.x;
    const int jj = tid & 15;
    const int hs = tid >> 4;                 // 0..15
    const int j = blockIdx.x * 16 + jj;
    float mz0 = 0.f, mz1 = 0.f, mz2 = 0.f, cz = 0.f;
    float mh0 = 0.f, mh1 = 0.f, mh2 = 0.f, ch = 0.f;
#pragma unroll
    for (int i = 0; i < 16; ++i) {
        const int h = hs * 16 + i;
        const float wz = Wz[h * NH + j];
        const float wh = Wh[h * NH + j];
        const float p0 = Wp[h];
        const float p1 = Wp[NH + h];
        const float p2 = Wp[2 * NH + h];
        const float bb = bp[h];
        mz0 = fmaf(p0, wz, mz0); mz1 = fmaf(p1, wz, mz1); mz2 = fmaf(p2, wz, mz2);
        cz  = fmaf(bb, wz, cz);
        mh0 = fmaf(p0, wh, mh0); mh1 = fmaf(p1, wh, mh1); mh2 = fmaf(p2, wh, mh2);
        ch  = fmaf(bb, wh, ch);
    }
    __shared__ float red[256][9];
    red[tid][0] = mz0; red[tid][1] = mz1; red[tid][2] = mz2; red[tid][3] = cz;
    red[tid][4] = mh0; red[tid][5] = mh1; red[tid][6] = mh2; red[tid][7] = ch;
    __syncthreads();
    if (tid < 16) {
        float v[8];
#pragma unroll
        for (int k = 0; k < 8; ++k) {
            float a = 0.f;
#pragma unroll
            for (int g = 0; g < 16; ++g) a += red[g * 16 + tid][k];
            v[k] = a;
        }
        v[3] += bz[j];
        v[7] += bh[j];
        const float SZ = -1.4426950408889634f;   // -log2(e)
        const float SH = -2.8853900817779268f;   // -2*log2(e)
        float4* w4 = (float4*)(wsW + j * 8);
        w4[0] = make_float4(v[0] * SZ, v[1] * SZ, v[2] * SZ, v[3] * SZ);
        w4[1] = make_float4(v[4] * SH, v[5] * SH, v[6] * SH, v[7] * SH);
    }
}

// Gate math for 2 timesteps from LDS x (broadcast ds_read2_b32 pairs).
// XC = pointer into LDS chunk (runtime base, compile-time element offsets).
// Outputs av (= 1-z) and bv (= z*tanh) packed pairs.
#define GATE2L(XC, U0, AV, BV)                                                  \
    {                                                                           \
        f32x2 xx_ = { (XC)[6*(U0)+0], (XC)[6*(U0)+3] };                         \
        f32x2 xy_ = { (XC)[6*(U0)+1], (XC)[6*(U0)+4] };                         \
        f32x2 xz_ = { (XC)[6*(U0)+2], (XC)[6*(U0)+5] };                         \
        const f32x2 s1_ = pkfma(xx_, wax, pkfma(xy_, way, pkfma(xz_, waz, waw)));\
        const f32x2 s2_ = pkfma(xx_, wbx, pkfma(xy_, wby, pkfma(xz_, wbz, wbw)));\
        f32x2 e1_, e2_;                                                         \
        e1_.x = fexp2(s1_.x); e1_.y = fexp2(s1_.y);                             \
        e2_.x = fexp2(s2_.x); e2_.y = fexp2(s2_.y);                             \
        const f32x2 d2_ = e2_ + 1.f;                                            \
        const f32x2 q_  = e1_ * d2_;                                            \
        const f32x2 den_ = q_ + d2_;       /* = d1*d2 */                        \
        const float rp_ = frcp(den_.x * den_.y);                                \
        f32x2 rr_; rr_.x = den_.y * rp_; rr_.y = den_.x * rp_;                  \
        AV = q_ * rr_;                     /* a = 1-z   */                      \
        BV = (1.f - e2_) * rr_;            /* b = z*tanh */                     \
    }

// ---------------------------------------------------------------------------
// Pass 1: per-(batch, segment) blocks (thread = channel). Segment composite
// (A, B): h_end = A*h_start + B. x staged once in LDS, pairs via ds_read2.
// ---------------------------------------------------------------------------
__global__ __launch_bounds__(256, 6) void pass1_seg(
        const float* __restrict__ x, const float* __restrict__ wsW,
        float* __restrict__ Aarr, float* __restrict__ Barr) {
    const int tid = threadIdx.x;
    const int b = blockIdx.x >> 5;           // NSEG = 32
    const int s = blockIdx.x & (NSEG - 1);

    const float4* wv = (const float4*)(wsW + tid * 8);
    const float4 wA4 = wv[0];
    const float4 wB4 = wv[1];
    const f32x2 wax = splat2(wA4.x), way = splat2(wA4.y), waz = splat2(wA4.z), waw = splat2(wA4.w);
    const f32x2 wbx = splat2(wB4.x), wby = splat2(wB4.y), wbz = splat2(wB4.z), wbw = splat2(wB4.w);

    __shared__ float xlds[SEGLEN * 3];       // 192 floats
    const float* xseg = x + ((size_t)b * NL + (size_t)s * SEGLEN) * 3;
    if (tid < SEGLEN * 3) xlds[tid] = xseg[tid];
    __syncthreads();

    f32x2 Apk = { 1.f, 1.f };
    float Bacc = 0.f;
    for (int c = 0; c < NCHK; ++c) {
        const float* xc = xlds + c * (RCHUNK * 3);
#pragma unroll
        for (int u0 = 0; u0 < 8; ++u0) {
            f32x2 av, bv;
            GATE2L(xc, u0, av, bv);
            Bacc = fmaf(av.x, Bacc, bv.x);
            Bacc = fmaf(av.y, Bacc, bv.y);
            Apk *= av;
        }
    }
    const size_t o = ((size_t)b * NSEG + s) * NH + tid;
    Aarr[o] = Apk.x * Apk.y;
    Barr[o] = Bacc;
}

// ---------------------------------------------------------------------------
// Pass 3: per-(batch, segment) blocks. Computes its own segment-start state
// from (A,B) prefixes, recomputes in-segment recurrence, emits preds.
// Pred-reduction over 256 channels via f16x2-packed LDS transpose per 16 t.
// Stage2 has NO rotation: addr = 9*(8g+j)+q -> exactly 2 lanes/bank (free).
// ---------------------------------------------------------------------------
__global__ __launch_bounds__(256, 6) void pass3_pred(
        const float* __restrict__ x, const float* __restrict__ wsW,
        const float* __restrict__ Wg, const float* __restrict__ bg,
        const float* __restrict__ Aarr, const float* __restrict__ Barr,
        float* __restrict__ out) {
    const int tid = threadIdx.x;
    const int b = blockIdx.x >> 5;
    const int s = blockIdx.x & (NSEG - 1);

    const float4* wv = (const float4*)(wsW + tid * 8);
    const float4 wA4 = wv[0];
    const float4 wB4 = wv[1];
    const f32x2 wax = splat2(wA4.x), way = splat2(wA4.y), waz = splat2(wA4.z), waw = splat2(wA4.w);
    const f32x2 wbx = splat2(wB4.x), wby = splat2(wB4.y), wbz = splat2(wB4.z), wbw = splat2(wB4.w);
    const float wg = Wg[tid];
    const float bgv = bg[0];

    __shared__ float xlds[SEGLEN * 3];
    __shared__ unsigned int pbuf[NH * PBPITCH];   // f16x2 pairs
    __shared__ float part2[32][18];
    __shared__ float part3[4][17];

    const float* xseg = x + ((size_t)b * NL + (size_t)s * SEGLEN) * 3;
    if (tid < SEGLEN * 3) xlds[tid] = xseg[tid];

    // ---- segment-start state: prefix over earlier segments' (A,B) ----
    float h = 0.f;
    {
        const size_t pbase = (size_t)b * NSEG * NH + tid;
        for (int k0 = 0; k0 < s; k0 += 8) {      // s uniform per block
            float Ak[8], Bk[8];
#pragma unroll
            for (int k = 0; k < 8; ++k) {
                const int kk = k0 + k;
                const bool u = kk < s;           // uniform predicate
                Ak[k] = u ? Aarr[pbase + (size_t)kk * NH] : 1.f;
                Bk[k] = u ? Barr[pbase + (size_t)kk * NH] : 0.f;
            }
#pragma unroll
            for (int k = 0; k < 8; ++k) h = fmaf(Ak[k], h, Bk[k]);
        }
    }
    __syncthreads();

    const int q   = tid & 7;                 // stage2: timestep-pair index
    const int grp = tid >> 3;                // stage2: channel group (8 ch)

    for (int c = 0; c < NCHK; ++c) {
        const float* xc = xlds + c * (RCHUNK * 3);
#pragma unroll
        for (int u0 = 0; u0 < 8; ++u0) {
            f32x2 av, bv;
            GATE2L(xc, u0, av, bv);
            const float p0 = h * wg;         // pred uses h BEFORE update
            h = fmaf(av.x, h, bv.x);
            const float p1 = h * wg;
            h = fmaf(av.y, h, bv.y);
            U32H2 pk; pk.h = __builtin_amdgcn_cvt_pkrtz(p0, p1);
            pbuf[tid * PBPITCH + u0] = pk.u; // stage 1 write (2-way banks)
        }
        __syncthreads();
        // stage 2: thread (grp,q) sums 8 channels for one t-pair, NO rotation
        f16x2 acc2 = (f16x2)0.f;
#pragma unroll
        for (int j = 0; j < 8; ++j) {
            U32H2 rd; rd.u = pbuf[(grp * 8 + j) * PBPITCH + q];
            acc2 += rd.h;
        }
        {
            f32x2 pr; pr.x = (float)acc2.x; pr.y = (float)acc2.y;
            *(f32x2*)&part2[grp][2 * q] = pr;
        }
        __syncthreads();
        // stage 3a: wave 0 reduces 32 groups -> 4 quads; 3b: final + bias
        if (tid < 64) {
            const int t2 = tid & 15, quad = tid >> 4;
            float a3 = 0.f;
#pragma unroll
            for (int g2 = 0; g2 < 8; ++g2)
                a3 += part2[quad * 8 + g2][t2];
            part3[quad][t2] = a3;
            if (tid < 16) {
                const float o = part3[0][tid] + part3[1][tid]
                              + part3[2][tid] + part3[3][tid] + bgv;
                out[(size_t)b * NL + (size_t)s * SEGLEN + c * RCHUNK + tid] = o;
            }
        }
        // pbuf/part2 reuse fenced by the two barriers above (stage3 wave joins
        // the next chunk's first barrier only after its part2/part3 reads).
    }
}

// ---------------------------------------------------------------------------
// Fallback (ws too small): monolithic scan, 128 blocks x 256 thr.
// ---------------------------------------------------------------------------
__global__ __launch_bounds__(256) void scan_kernel_nows(
        const float* __restrict__ x, const float* __restrict__ wsW,
        const float* __restrict__ Wg, const float* __restrict__ bg,
        float* __restrict__ out) {
    const int tid  = threadIdx.x;
    const int lane = tid & 63;
    const int wid  = tid >> 6;
    const int b = blockIdx.x;

    const float4* wv = (const float4*)(wsW + tid * 8);
    const float4 wA = wv[0];
    const float4 wB = wv[1];
    const float  wg = Wg[tid];
    const float  bgv = bg[0];

    const float* xb = x + (size_t)b * (NL * 3);

    __shared__ float4 xbuf[2][CHUNK];
    __shared__ float  predbuf[2][4][CHUNK];
    float* xbf = (float*)xbuf;

    const int sw = tid;
    const int sidx = (sw / 3) * 4 + (sw % 3);

    if (tid < WORDS) xbf[sidx] = xb[sw];
    __syncthreads();

    float h = 0.f;
    for (int c = 0; c < NCHUNK; ++c) {
        const int cur = c & 1;
        float nv = 0.f;
        if (tid < WORDS && c + 1 < NCHUNK) nv = xb[(c + 1) * WORDS + sw];

        float p[CHUNK];
        const float4* xc = xbuf[cur];
#pragma unroll
        for (int t = 0; t < CHUNK; ++t) {
            const float4 xv = xc[t];
            const float e1 = fexp2(fmaf(xv.x, wA.x, fmaf(xv.y, wA.y, fmaf(xv.z, wA.z, wA.w))));
            const float e2 = fexp2(fmaf(xv.x, wB.x, fmaf(xv.y, wB.y, fmaf(xv.z, wB.z, wB.w))));
            const float d2 = 1.f + e2;
            const float e1d2 = e1 * d2;
            const float r  = frcp(e1d2 + d2);
            p[t] = h * wg;
            h = fmaf(e1d2 * r, h, (1.f - e2) * r);
        }
#pragma unroll
        for (int t = 0; t < CHUNK; ++t) {
            float v = p[t];
            v += __shfl_xor(v, 1, 64);
            v += __shfl_xor(v, 2, 64);
            v += __shfl_xor(v, 4, 64);
            v += __shfl_xor(v, 8, 64);
            v += __shfl_xor(v, 16, 64);
            v += __shfl_xor(v, 32, 64);
            p[t] = v;
        }
        if (lane == 0) {
            float4* dpr = (float4*)&predbuf[cur][wid][0];
#pragma unroll
            for (int j2 = 0; j2 < CHUNK / 4; ++j2)
                dpr[j2] = make_float4(p[4*j2], p[4*j2+1], p[4*j2+2], p[4*j2+3]);
        }
        if (tid < WORDS && c + 1 < NCHUNK) xbf[(cur ^ 1) * CHUNK * 4 + sidx] = nv;
        __syncthreads();
        if (tid < CHUNK) {
            const float ssum = predbuf[cur][0][tid] + predbuf[cur][1][tid]
                             + predbuf[cur][2][tid] + predbuf[cur][3][tid];
            out[(size_t)b * NL + c * CHUNK + tid] = ssum + bgv;
        }
    }
}

extern "C" void kernel_launch(void* const* d_in, const int* in_sizes, int n_in,
                              void* d_out, int out_size, void* d_ws, size_t ws_size,
                              hipStream_t stream) {
    const float* x  = (const float*)d_in[0];
    const float* Wp = (const float*)d_in[1];
    const float* bp = (const float*)d_in[2];
    const float* Wz = (const float*)d_in[3];
    const float* bz = (const float*)d_in[4];
    const float* Wh = (const float*)d_in[5];
    const float* bh = (const float*)d_in[6];
    const float* Wg = (const float*)d_in[7];
    const float* bg = (const float*)d_in[8];
    float* out = (float*)d_out;

    float* wsW = (float*)d_ws;                       // 8 KB folded weights

    fold_kernel<<<16, 256, 0, stream>>>(Wp, bp, Wz, bz, Wh, bh, wsW);

    const size_t need = (size_t)(8 * NH) * sizeof(float)
                      + (size_t)2 * NB * NSEG * NH * sizeof(float);
    if (ws_size >= need) {
        float* Aarr = wsW + 8 * NH;
        float* Barr = Aarr + (size_t)NB * NSEG * NH;
        pass1_seg<<<NB * NSEG, 256, 0, stream>>>(x, wsW, Aarr, Barr);
        pass3_pred<<<NB * NSEG, 256, 0, stream>>>(x, wsW, Wg, bg, Aarr, Barr, out);
    } else {
        scan_kernel_nows<<<NB, 256, 0, stream>>>(x, wsW, Wg, bg, out);
    }
}

// Round 8
// 75.796 us; speedup vs baseline: 1.0763x; 1.0763x over previous
//
#include <hip/hip_runtime.h>

#define NB 128
#define NL 2048
#define NH 256
#define NSEG 16
#define SEGLEN (NL / NSEG)   // 128
#define RCHUNK 32            // timesteps per reduce-chunk in pass3
#define PBPITCH 17           // uints per channel row in pbuf (odd -> 2-way banks)
#define CHUNK 32             // fallback kernel chunking
#define NCHUNK (NL / CHUNK)
#define WORDS (CHUNK * 3)

typedef float f32x2 __attribute__((ext_vector_type(2)));
typedef __fp16 f16x2 __attribute__((ext_vector_type(2)));

__device__ __forceinline__ float fexp2(float v) { return __builtin_amdgcn_exp2f(v); }
__device__ __forceinline__ float frcp(float v)  { return __builtin_amdgcn_rcpf(v); }

__device__ __forceinline__ f32x2 pkfma(f32x2 a, f32x2 b, f32x2 c) {
#if __has_builtin(__builtin_elementwise_fma)
    return __builtin_elementwise_fma(a, b, c);
#else
    f32x2 r; r.x = fmaf(a.x, b.x, c.x); r.y = fmaf(a.y, b.y, c.y); return r;
#endif
}
__device__ __forceinline__ f32x2 splat2(float v) { f32x2 r; r.x = v; r.y = v; return r; }

union U32H2 { unsigned int u; f16x2 h; };

// ---------------------------------------------------------------------------
// Fold K=3 projection through Wz/Wh, pre-scaled by exp2 constants.
// ---------------------------------------------------------------------------
__global__ __launch_bounds__(256) void fold_kernel(
        const float* __restrict__ Wp, const float* __restrict__ bp,
        const float* __restrict__ Wz, const float* __restrict__ bz,
        const float* __restrict__ Wh, const float* __restrict__ bh,
        float* __restrict__ wsW) {
    const int tid = threadIdx.x;
    const int jj = tid & 15;
    const int hs = tid >> 4;                 // 0..15
    const int j = blockIdx.x * 16 + jj;
    float mz0 = 0.f, mz1 = 0.f, mz2 = 0.f, cz = 0.f;
    float mh0 = 0.f, mh1 = 0.f, mh2 = 0.f, ch = 0.f;
#pragma unroll
    for (int i = 0; i < 16; ++i) {
        const int h = hs * 16 + i;
        const float wz = Wz[h * NH + j];
        const float wh = Wh[h * NH + j];
        const float p0 = Wp[h];
        const float p1 = Wp[NH + h];
        const float p2 = Wp[2 * NH + h];
        const float bb = bp[h];
        mz0 = fmaf(p0, wz, mz0); mz1 = fmaf(p1, wz, mz1); mz2 = fmaf(p2, wz, mz2);
        cz  = fmaf(bb, wz, cz);
        mh0 = fmaf(p0, wh, mh0); mh1 = fmaf(p1, wh, mh1); mh2 = fmaf(p2, wh, mh2);
        ch  = fmaf(bb, wh, ch);
    }
    __shared__ float red[256][9];
    red[tid][0] = mz0; red[tid][1] = mz1; red[tid][2] = mz2; red[tid][3] = cz;
    red[tid][4] = mh0; red[tid][5] = mh1; red[tid][6] = mh2; red[tid][7] = ch;
    __syncthreads();
    if (tid < 16) {
        float v[8];
#pragma unroll
        for (int k = 0; k < 8; ++k) {
            float a = 0.f;
#pragma unroll
            for (int g = 0; g < 16; ++g) a += red[g * 16 + tid][k];
            v[k] = a;
        }
        v[3] += bz[j];
        v[7] += bh[j];
        const float SZ = -1.4426950408889634f;   // -log2(e)
        const float SH = -2.8853900817779268f;   // -2*log2(e)
        float4* w4 = (float4*)(wsW + j * 8);
        w4[0] = make_float4(v[0] * SZ, v[1] * SZ, v[2] * SZ, v[3] * SZ);
        w4[1] = make_float4(v[4] * SH, v[5] * SH, v[6] * SH, v[7] * SH);
    }
}

// Gate math for 2 timesteps. XQ = float4[6] (8 timesteps), U0 in 0..3.
#define GATE2(XQ, U0, AV, BV)                                                   \
    {                                                                           \
        const float* xf_ = (const float*)(XQ);                                  \
        f32x2 xx_ = { xf_[6*(U0)+0], xf_[6*(U0)+3] };                           \
        f32x2 xy_ = { xf_[6*(U0)+1], xf_[6*(U0)+4] };                           \
        f32x2 xz_ = { xf_[6*(U0)+2], xf_[6*(U0)+5] };                           \
        const f32x2 s1_ = pkfma(xx_, wax, pkfma(xy_, way, pkfma(xz_, waz, waw)));\
        const f32x2 s2_ = pkfma(xx_, wbx, pkfma(xy_, wby, pkfma(xz_, wbz, wbw)));\
        f32x2 e1_, e2_;                                                         \
        e1_.x = fexp2(s1_.x); e1_.y = fexp2(s1_.y);                             \
        e2_.x = fexp2(s2_.x); e2_.y = fexp2(s2_.y);                             \
        const f32x2 d2_ = e2_ + 1.f;                                            \
        const f32x2 q_  = e1_ * d2_;                                            \
        const f32x2 den_ = q_ + d2_;       /* = d1*d2 */                        \
        const float rp_ = frcp(den_.x * den_.y);                                \
        f32x2 rr_; rr_.x = den_.y * rp_; rr_.y = den_.x * rp_;                  \
        AV = q_ * rr_;                     /* a = 1-z    */                     \
        BV = (1.f - e2_) * rr_;            /* b = z*tanh */                     \
    }

#define LOAD8(XQ, SC)                                                           \
    _Pragma("unroll")                                                           \
    for (int i_ = 0; i_ < 6; ++i_) XQ[i_] = xs4[(SC) * 6 + i_];

// ---------------------------------------------------------------------------
// Pass 1: per-(batch, segment) blocks (thread = channel). Segment composite
// (A, B): h_end = A*h_start + B. x via block-uniform register loads,
// double-buffered 8-timestep sub-chunks (compile-time indexed).
// ---------------------------------------------------------------------------
__global__ __launch_bounds__(256, 4) void pass1_seg(
        const float* __restrict__ x, const float* __restrict__ wsW,
        float* __restrict__ Aarr, float* __restrict__ Barr) {
    const int tid = threadIdx.x;
    const int b = blockIdx.x >> 4;           // NSEG = 16
    const int s = blockIdx.x & (NSEG - 1);

    const float4* wv = (const float4*)(wsW + tid * 8);
    const float4 wA4 = wv[0];
    const float4 wB4 = wv[1];
    const f32x2 wax = splat2(wA4.x), way = splat2(wA4.y), waz = splat2(wA4.z), waw = splat2(wA4.w);
    const f32x2 wbx = splat2(wB4.x), wby = splat2(wB4.y), wbz = splat2(wB4.z), wbw = splat2(wB4.w);

    const float4* xs4 = (const float4*)(x + ((size_t)b * NL + (size_t)s * SEGLEN) * 3);

#define P1_BODY(XQ)                                                             \
    _Pragma("unroll")                                                           \
    for (int u0 = 0; u0 < 4; ++u0) {                                            \
        f32x2 av, bv;                                                           \
        GATE2(XQ, u0, av, bv);                                                  \
        Bacc = fmaf(av.x, Bacc, bv.x);                                          \
        Bacc = fmaf(av.y, Bacc, bv.y);                                          \
        A *= av.x * av.y;                                                       \
    }

    float A = 1.f, Bacc = 0.f;
    float4 xa[6], xb[6];
    LOAD8(xa, 0);
    for (int c = 0; c < 8; ++c) {            // 16 timesteps per iter
        LOAD8(xb, 2 * c + 1);
        P1_BODY(xa);
        const int nxt = (c < 7) ? (2 * c + 2) : 0;
        LOAD8(xa, nxt);
        P1_BODY(xb);
    }
    const size_t o = ((size_t)b * NSEG + s) * NH + tid;
    Aarr[o] = A;
    Barr[o] = Bacc;
#undef P1_BODY
}

// ---------------------------------------------------------------------------
// Pass 3: per-(batch, segment) blocks. Computes its own segment-start state
// from (A,B) prefixes, recomputes in-segment recurrence, emits preds.
// Pred-reduction over 256 channels via f16x2-packed LDS transpose per 32 t
// (16 t-pairs x 16 channel-groups, no rotation, pitch-17 -> 2-way banks).
// ---------------------------------------------------------------------------
__global__ __launch_bounds__(256, 4) void pass3_pred(
        const float* __restrict__ x, const float* __restrict__ wsW,
        const float* __restrict__ Wg, const float* __restrict__ bg,
        const float* __restrict__ Aarr, const float* __restrict__ Barr,
        float* __restrict__ out) {
    const int tid = threadIdx.x;
    const int b = blockIdx.x >> 4;
    const int s = blockIdx.x & (NSEG - 1);

    const float4* wv = (const float4*)(wsW + tid * 8);
    const float4 wA4 = wv[0];
    const float4 wB4 = wv[1];
    const f32x2 wax = splat2(wA4.x), way = splat2(wA4.y), waz = splat2(wA4.z), waw = splat2(wA4.w);
    const f32x2 wbx = splat2(wB4.x), wby = splat2(wB4.y), wbz = splat2(wB4.z), wbw = splat2(wB4.w);
    const float wg = Wg[tid];
    const float bgv = bg[0];

    // ---- segment-start state: prefix over earlier segments' (A,B) ----
    float h = 0.f;
    {
        const size_t pbase = (size_t)b * NSEG * NH + tid;
        for (int k0 = 0; k0 < NSEG; k0 += 8) {
            float Ak[8], Bk[8];
#pragma unroll
            for (int k = 0; k < 8; ++k) {
                const int kk = k0 + k;
                const bool u = kk < s;           // uniform predicate
                Ak[k] = u ? Aarr[pbase + (size_t)kk * NH] : 1.f;
                Bk[k] = u ? Barr[pbase + (size_t)kk * NH] : 0.f;
            }
#pragma unroll
            for (int k = 0; k < 8; ++k) h = fmaf(Ak[k], h, Bk[k]);
        }
    }

    const float4* xs4 = (const float4*)(x + ((size_t)b * NL + (size_t)s * SEGLEN) * 3);

    __shared__ unsigned int pbuf[NH * PBPITCH];   // f16x2 t-pairs, 17408 B
    __shared__ unsigned int part2[16 * PBPITCH];  // [grp][q] f16x2, 1088 B

    const int q   = tid & 15;                // stage2: t-pair index (0..15)
    const int grp = tid >> 4;                // stage2: channel group (16 ch)

    // Gate+pred for 8 timesteps; packs preds as f16x2 pairs into pbuf rows.
#define P3_BODY(XQ, Q0)                                                         \
    _Pragma("unroll")                                                           \
    for (int u0 = 0; u0 < 4; ++u0) {                                            \
        f32x2 av, bv;                                                           \
        GATE2(XQ, u0, av, bv);                                                  \
        const float p0_ = h * wg;            /* pred uses h BEFORE update */    \
        h = fmaf(av.x, h, bv.x);                                                \
        const float p1_ = h * wg;                                               \
        h = fmaf(av.y, h, bv.y);                                                \
        U32H2 pk_; pk_.h = __builtin_amdgcn_cvt_pkrtz(p0_, p1_);                \
        pbuf[tid * PBPITCH + (Q0) + u0] = pk_.u;                                \
    }

    float4 xa[6], xb[6];
    LOAD8(xa, 0);
    for (int c2 = 0; c2 < 4; ++c2) {         // 32 timesteps per iter
        // first 16 t of the chunk -> pbuf slots 0..7
        LOAD8(xb, 4 * c2 + 1);
        P3_BODY(xa, 0);
        LOAD8(xa, 4 * c2 + 2);
        P3_BODY(xb, 4);
        // second 16 t -> slots 8..15
        LOAD8(xb, 4 * c2 + 3);
        P3_BODY(xa, 8);
        {
            const int nxt = (c2 < 3) ? (4 * c2 + 4) : 0;
            LOAD8(xa, nxt);
        }
        P3_BODY(xb, 12);
        __syncthreads();
        // stage 2: thread (grp,q) sums 16 channels for t-pair q (pk_add_f16)
        {
            f16x2 acc2 = (f16x2)0.f;
#pragma unroll
            for (int j = 0; j < 16; ++j) {
                U32H2 rd; rd.u = pbuf[(grp * 16 + j) * PBPITCH + q];
                acc2 += rd.h;
            }
            U32H2 wr; wr.h = acc2;
            part2[grp * PBPITCH + q] = wr.u;
        }
        __syncthreads();
        // stage 3: 16 threads sum 16 group-partials for their t-pair + bias
        if (tid < 16) {
            f16x2 a3 = (f16x2)0.f;
#pragma unroll
            for (int g2 = 0; g2 < 16; ++g2) {
                U32H2 rd; rd.u = part2[g2 * PBPITCH + tid];
                a3 += rd.h;
            }
            float2 o2;
            o2.x = (float)a3.x + bgv;
            o2.y = (float)a3.y + bgv;
            *(float2*)&out[(size_t)b * NL + (size_t)s * SEGLEN + c2 * RCHUNK + 2 * tid] = o2;
        }
        // pbuf reuse (next stage1) is safe: all stage-2 reads complete before
        // the 2nd barrier. part2 reuse is safe: stage-3 (wave 0) reads finish
        // before wave 0 reaches the next chunk's first barrier.
    }
#undef P3_BODY
}

// ---------------------------------------------------------------------------
// Fallback (ws too small): monolithic scan, 128 blocks x 256 thr.
// ---------------------------------------------------------------------------
__global__ __launch_bounds__(256) void scan_kernel_nows(
        const float* __restrict__ x, const float* __restrict__ wsW,
        const float* __restrict__ Wg, const float* __restrict__ bg,
        float* __restrict__ out) {
    const int tid  = threadIdx.x;
    const int lane = tid & 63;
    const int wid  = tid >> 6;
    const int b = blockIdx.x;

    const float4* wv = (const float4*)(wsW + tid * 8);
    const float4 wA = wv[0];
    const float4 wB = wv[1];
    const float  wg = Wg[tid];
    const float  bgv = bg[0];

    const float* xb = x + (size_t)b * (NL * 3);

    __shared__ float4 xbuf[2][CHUNK];
    __shared__ float  predbuf[2][4][CHUNK];
    float* xbf = (float*)xbuf;

    const int sw = tid;
    const int sidx = (sw / 3) * 4 + (sw % 3);

    if (tid < WORDS) xbf[sidx] = xb[sw];
    __syncthreads();

    float h = 0.f;
    for (int c = 0; c < NCHUNK; ++c) {
        const int cur = c & 1;
        float nv = 0.f;
        if (tid < WORDS && c + 1 < NCHUNK) nv = xb[(c + 1) * WORDS + sw];

        float p[CHUNK];
        const float4* xc = xbuf[cur];
#pragma unroll
        for (int t = 0; t < CHUNK; ++t) {
            const float4 xv = xc[t];
            const float e1 = fexp2(fmaf(xv.x, wA.x, fmaf(xv.y, wA.y, fmaf(xv.z, wA.z, wA.w))));
            const float e2 = fexp2(fmaf(xv.x, wB.x, fmaf(xv.y, wB.y, fmaf(xv.z, wB.z, wB.w))));
            const float d2 = 1.f + e2;
            const float e1d2 = e1 * d2;
            const float r  = frcp(e1d2 + d2);
            p[t] = h * wg;
            h = fmaf(e1d2 * r, h, (1.f - e2) * r);
        }
#pragma unroll
        for (int t = 0; t < CHUNK; ++t) {
            float v = p[t];
            v += __shfl_xor(v, 1, 64);
            v += __shfl_xor(v, 2, 64);
            v += __shfl_xor(v, 4, 64);
            v += __shfl_xor(v, 8, 64);
            v += __shfl_xor(v, 16, 64);
            v += __shfl_xor(v, 32, 64);
            p[t] = v;
        }
        if (lane == 0) {
            float4* dpr = (float4*)&predbuf[cur][wid][0];
#pragma unroll
            for (int j2 = 0; j2 < CHUNK / 4; ++j2)
                dpr[j2] = make_float4(p[4*j2], p[4*j2+1], p[4*j2+2], p[4*j2+3]);
        }
        if (tid < WORDS && c + 1 < NCHUNK) xbf[(cur ^ 1) * CHUNK * 4 + sidx] = nv;
        __syncthreads();
        if (tid < CHUNK) {
            const float ssum = predbuf[cur][0][tid] + predbuf[cur][1][tid]
                             + predbuf[cur][2][tid] + predbuf[cur][3][tid];
            out[(size_t)b * NL + c * CHUNK + tid] = ssum + bgv;
        }
    }
}

extern "C" void kernel_launch(void* const* d_in, const int* in_sizes, int n_in,
                              void* d_out, int out_size, void* d_ws, size_t ws_size,
                              hipStream_t stream) {
    const float* x  = (const float*)d_in[0];
    const float* Wp = (const float*)d_in[1];
    const float* bp = (const float*)d_in[2];
    const float* Wz = (const float*)d_in[3];
    const float* bz = (const float*)d_in[4];
    const float* Wh = (const float*)d_in[5];
    const float* bh = (const float*)d_in[6];
    const float* Wg = (const float*)d_in[7];
    const float* bg = (const float*)d_in[8];
    float* out = (float*)d_out;

    float* wsW = (float*)d_ws;                       // 8 KB folded weights

    fold_kernel<<<16, 256, 0, stream>>>(Wp, bp, Wz, bz, Wh, bh, wsW);

    const size_t need = (size_t)(8 * NH) * sizeof(float)
                      + (size_t)2 * NB * NSEG * NH * sizeof(float);
    if (ws_size >= need) {
        float* Aarr = wsW + 8 * NH;
        float* Barr = Aarr + (size_t)NB * NSEG * NH;
        pass1_seg<<<NB * NSEG, 256, 0, stream>>>(x, wsW, Aarr, Barr);
        pass3_pred<<<NB * NSEG, 256, 0, stream>>>(x, wsW, Wg, bg, Aarr, Barr, out);
    } else {
        scan_kernel_nows<<<NB, 256, 0, stream>>>(x, wsW, Wg, bg, out);
    }
}